// Round 8
// baseline (309.662 us; speedup 1.0000x reference)
//
#include <hip/hip_runtime.h>

// MADE / PixelCNN autoregressive inverse (all fp32, per reference).
//
// r0-r4: 6-barrier/16-wave skeleton pinned at ~179us regardless of inner
// loops. r5: 2-barrier/4-wave correct but spilled (336 floats vs 256-VGPR).
// r7: 2-barrier/8-wave spine+helpers: 146.5us, bit-exact, no spill. Post-
// mortem: active-CU VALU ~43%; all 4 off-center taps x 2 layers x 2 nets
// still recomputed INSIDE every pixel slot at 2 instr/MAC.
//
// r8: row-ahead N-tap pipeline. The NW/N/NE taps of both conv layers depend
// only on row i-1, not on the serial pixel chain. Helper waves batch-compute
// ntap[r][c] = 3-tap dot vs h(row r-1) for ALL 8 cols of the NEXT row while
// the spine decodes the current row (task (r,c): c<=5 at slot (r-1,c+2),
// c=6,7 at slots (r,0),(r,1); consumed at slot (r,c); 2-col lag, row-parity
// double buffer -> race-free under the same 2-barrier cadence). Only the
// W-tap (left neighbor) + center columns remain per-pixel:
//  S : epi(p-1), h0(p), center-c1 (readlane on own h0v) | B1 | h1, center-c2,
//      h2, 1x1-out butterfly, xchg | B2.
//  A : wtap0 = W1_W . h0(p-1), wtap1 = W2_W . h1(p-1)  (pre-B1; j==0 -> 0).
//  H0: W1 N-taps task of the slot's schedule (1 DOT16 pre-B1, 2 post-B1).
//  H1: same for W2 vs h1row.
// h1 = elu(((c1+b1) + ntap0) + wtap0)  (same assoc. grouping as r7 -> h1
// bit-exact; h2 grouping differs from r7 by ulps, well within tolerance).

#define NT 512

__device__ __forceinline__ float elu(float x) { return x > 0.f ? x : expm1f(x); }

__device__ __forceinline__ float rdlane(float v, int l) {
  return __int_as_float(__builtin_amdgcn_readlane(__float_as_int(v), l));
}

#define BAR() asm volatile("s_waitcnt lgkmcnt(0)\n\ts_barrier" ::: "memory")

// one 64-dot quarter-step: acc{0..3} += W_[4q+m] * (lane-q broadcast of F_ members)
#define DOT16(W_, F_)                                                \
  _Pragma("unroll")                                                  \
  for (int q = 0; q < 16; ++q) {                                     \
    a0 += (W_)[4*q+0] * rdlane((F_).x, q);                           \
    a1 += (W_)[4*q+1] * rdlane((F_).y, q);                           \
    a2 += (W_)[4*q+2] * rdlane((F_).z, q);                           \
    a3 += (W_)[4*q+3] * rdlane((F_).w, q);                           \
  }

__global__ __launch_bounds__(NT)
__attribute__((amdgpu_waves_per_eu(2, 2)))
void made_ar_decode_k(
    const float* __restrict__ x,
    const float* __restrict__ mw0, const float* __restrict__ mb0,
    const float* __restrict__ mw1, const float* __restrict__ mb1,
    const float* __restrict__ mw2, const float* __restrict__ mb2,
    const float* __restrict__ mwo, const float* __restrict__ mbo,
    const float* __restrict__ lw0, const float* __restrict__ lb0,
    const float* __restrict__ lw1, const float* __restrict__ lb1,
    const float* __restrict__ lw2, const float* __restrict__ lb2,
    const float* __restrict__ lwo, const float* __restrict__ lbo,
    float* __restrict__ out)
{
  const int b    = blockIdx.x;
  const int tid  = threadIdx.x;
  const int wave = tid >> 6;       // 0..7
  const int role = wave >> 1;      // 0:S  1:A  2:H0  3:H1
  const int net  = wave & 1;       // 0 = mu, 1 = lv
  const int ch   = tid & 63;       // lane == out channel

  // row caches, parity double-buffered; padded col = spatial col + 1;
  // pad cols 0 and 9 never written -> permanent zeros ('SAME' border).
  __shared__ __align__(16) float h0row[2][2][10][64]; // [net][par][pcol][ch]
  __shared__ __align__(16) float h1row[2][2][10][64];
  __shared__ __align__(16) float yb[2][9][10][4];     // [net][prow][pcol][c]
  __shared__ __align__(16) float xchg[2][2][4];       // [p&1][net][c] raw sums
  __shared__ float wtap0[2][64], wtap1[2][64];        // [net][ch] W-tap dots
  __shared__ __align__(16) float ntap0[2][2][8][64];  // [net][rowpar][col][ch]
  __shared__ __align__(16) float ntap1[2][2][8][64];
  __shared__ float xls[256];

  for (int k = tid; k < 2*2*10*64; k += NT) {
    (&h0row[0][0][0][0])[k] = 0.f;
    (&h1row[0][0][0][0])[k] = 0.f;
  }
  for (int k = tid; k < 2*2*8*64; k += NT) {
    (&ntap0[0][0][0][0])[k] = 0.f;   // row 0 N-taps = 0
    (&ntap1[0][0][0][0])[k] = 0.f;
  }
  for (int k = tid; k < 2*9*10*4; k += NT) (&yb[0][0][0][0])[k] = 0.f;
  if (tid < 256) xls[tid] = x[b*256 + tid];   // [c][i][j] flat = c*64 + p

  __syncthreads();   // uniform join after init

  if (role == 0) {
    // ================= S: serial spine =================
    const float* w0g = net ? lw0 : mw0;
    const float* w1g = net ? lw1 : mw1;
    const float* w2g = net ? lw2 : mw2;
    const float* wog = net ? lwo : mwo;
    const int KH[4] = {0,0,0,1};
    const int KW[4] = {0,1,2,0};
    float waux[16], wc1[64], wc2[64], wo4[4];
#pragma unroll
    for (int t = 0; t < 4; ++t)
#pragma unroll
      for (int ic = 0; ic < 4; ++ic)
        waux[t*4 + ic] = w0g[((ch*4 + ic)*3 + KH[t])*3 + KW[t]];
#pragma unroll
    for (int q = 0; q < 64; ++q) wc1[q] = w1g[((ch*64 + q)*3 + 1)*3 + 1];
#pragma unroll
    for (int q = 0; q < 64; ++q) wc2[q] = w2g[((ch*64 + q)*3 + 1)*3 + 1];
#pragma unroll
    for (int c = 0; c < 4; ++c) wo4[c] = wog[c*64 + ch];
    float bA = (net ? lb0 : mb0)[ch];
    float bB = (net ? lb1 : mb1)[ch];
    float bC = (net ? lb2 : mb2)[ch];
    float boM[4], boL[4];
#pragma unroll
    for (int c = 0; c < 4; ++c) { boM[c] = mbo[c]; boL[c] = lbo[c]; }
#pragma unroll
    for (int k = 0; k < 16; ++k) asm volatile("" : "+v"(waux[k]));
#pragma unroll
    for (int q = 0; q < 64; ++q) asm volatile("" : "+v"(wc1[q]));
#pragma unroll
    for (int q = 0; q < 64; ++q) asm volatile("" : "+v"(wc2[q]));

    float lsacc = 0.f;

#pragma unroll 1
    for (int p = 0; p < 64; ++p) {
      const int i = p >> 3, j = p & 7, cur = i & 1;

      // ---- pre-B1: y-epilogue of p-1, h0(p), center-c1 ----
      if (p > 0) {
        const int pp = p - 1;
        const float4 m4 = *reinterpret_cast<const float4*>(&xchg[pp & 1][0][0]);
        const float4 l4 = *reinterpret_cast<const float4*>(&xchg[pp & 1][1][0]);
        float y0 = (xls[0*64+pp] - (m4.x + boM[0])) / (expf(0.5f*(l4.x + boL[0])) + 1e-12f);
        float y1 = (xls[1*64+pp] - (m4.y + boM[1])) / (expf(0.5f*(l4.y + boL[1])) + 1e-12f);
        float y2 = (xls[2*64+pp] - (m4.z + boM[2])) / (expf(0.5f*(l4.z + boL[2])) + 1e-12f);
        float y3 = (xls[3*64+pp] - (m4.w + boM[3])) / (expf(0.5f*(l4.w + boL[3])) + 1e-12f);
        if (ch == 0)
          *reinterpret_cast<float4*>(&yb[net][(pp>>3)+1][(pp&7)+1][0]) =
              make_float4(y0, y1, y2, y3);
      }
      float acc = bA;
#pragma unroll
      for (int t = 0; t < 4; ++t) {
        const float4 yv = *reinterpret_cast<const float4*>(&yb[net][i + KH[t]][j + KW[t]][0]);
        acc += waux[t*4+0]*yv.x + waux[t*4+1]*yv.y
             + waux[t*4+2]*yv.z + waux[t*4+3]*yv.w;
      }
      const float h0v = elu(acc);
      h0row[net][cur][j + 1][ch] = h0v;

      float a0 = 0.f, a1 = 0.f, a2 = 0.f, a3 = 0.f;
#pragma unroll
      for (int q = 0; q < 16; ++q) {
        a0 += wc1[4*q+0] * rdlane(h0v, 4*q+0);
        a1 += wc1[4*q+1] * rdlane(h0v, 4*q+1);
        a2 += wc1[4*q+2] * rdlane(h0v, 4*q+2);
        a3 += wc1[4*q+3] * rdlane(h0v, 4*q+3);
      }
      const float c1 = (a0 + a1) + (a2 + a3);

      BAR();   // B1: wtap0/wtap1(p) visible (ntap was ready a row ago)

      // ---- post-B1: h1, center-c2, h2, out-conv ----
      const float h1v = elu(((c1 + bB) + ntap0[net][cur][j][ch]) + wtap0[net][ch]);
      h1row[net][cur][j + 1][ch] = h1v;

      a0 = 0.f; a1 = 0.f; a2 = 0.f; a3 = 0.f;
#pragma unroll
      for (int q = 0; q < 16; ++q) {
        a0 += wc2[4*q+0] * rdlane(h1v, 4*q+0);
        a1 += wc2[4*q+1] * rdlane(h1v, 4*q+1);
        a2 += wc2[4*q+2] * rdlane(h1v, 4*q+2);
        a3 += wc2[4*q+3] * rdlane(h1v, 4*q+3);
      }
      const float c2 = (a0 + a1) + (a2 + a3);
      const float h2v = elu(((c2 + bC) + ntap1[net][cur][j][ch]) + wtap1[net][ch]);

      float s0 = wo4[0]*h2v, s1 = wo4[1]*h2v, s2 = wo4[2]*h2v, s3 = wo4[3]*h2v;
#pragma unroll
      for (int off = 32; off; off >>= 1) {
        s0 += __shfl_xor(s0, off, 64);
        s1 += __shfl_xor(s1, off, 64);
        s2 += __shfl_xor(s2, off, 64);
        s3 += __shfl_xor(s3, off, 64);
      }
      if (ch == 0)
        *reinterpret_cast<float4*>(&xchg[p & 1][net][0]) = make_float4(s0, s1, s2, s3);
      if (net == 1 && ch == 0)
        lsacc += 0.5f*((s0 + boL[0]) + (s1 + boL[1]) + (s2 + boL[2]) + (s3 + boL[3]));

      BAR();   // B2: h1(p), xchg(p) visible
    }

    // final y(63) into yb (for the copy-out)
    {
      const float4 m4 = *reinterpret_cast<const float4*>(&xchg[1][0][0]);
      const float4 l4 = *reinterpret_cast<const float4*>(&xchg[1][1][0]);
      float y0 = (xls[0*64+63] - (m4.x + boM[0])) / (expf(0.5f*(l4.x + boL[0])) + 1e-12f);
      float y1 = (xls[1*64+63] - (m4.y + boM[1])) / (expf(0.5f*(l4.y + boL[1])) + 1e-12f);
      float y2 = (xls[2*64+63] - (m4.z + boM[2])) / (expf(0.5f*(l4.z + boL[2])) + 1e-12f);
      float y3 = (xls[3*64+63] - (m4.w + boM[3])) / (expf(0.5f*(l4.w + boL[3])) + 1e-12f);
      if (ch == 0)
        *reinterpret_cast<float4*>(&yb[net][8][8][0]) = make_float4(y0, y1, y2, y3);
    }
    if (net == 1 && ch == 0) out[32*4*64 + b] = lsacc;

  } else if (role == 1) {
    // ========== A: W-tap assist (wtap0 = W1_W.h0(p-1), wtap1 = W2_W.h1(p-1)) ==========
    const float* w1g = net ? lw1 : mw1;
    const float* w2g = net ? lw2 : mw2;
    float wW1[64], wW2[64];
#pragma unroll
    for (int q = 0; q < 64; ++q) {
      wW1[q] = w1g[((ch*64 + q)*3 + 1)*3 + 0];
      wW2[q] = w2g[((ch*64 + q)*3 + 1)*3 + 0];
    }
#pragma unroll
    for (int q = 0; q < 64; ++q) {
      asm volatile("" : "+v"(wW1[q]));
      asm volatile("" : "+v"(wW2[q]));
    }
#pragma unroll 1
    for (int p = 0; p < 64; ++p) {
      const int i = p >> 3, j = p & 7, cur = i & 1;
      float t0 = 0.f, t1 = 0.f;
      if (j > 0) {
        const float4 f0 = reinterpret_cast<const float4*>(&h0row[net][cur][j][0])[ch & 15];
        const float4 f1 = reinterpret_cast<const float4*>(&h1row[net][cur][j][0])[ch & 15];
        {
          float a0 = 0.f, a1 = 0.f, a2 = 0.f, a3 = 0.f;
          DOT16(wW1, f0);
          t0 = (a0 + a1) + (a2 + a3);
        }
        {
          float a0 = 0.f, a1 = 0.f, a2 = 0.f, a3 = 0.f;
          DOT16(wW2, f1);
          t1 = (a0 + a1) + (a2 + a3);
        }
      }
      wtap0[net][ch] = t0;
      wtap1[net][ch] = t1;
      BAR();
      BAR();
    }

  } else if (role == 2) {
    // ========== H0: W1 N-taps, one column task per slot (row-ahead) ==========
    const float* w1g = net ? lw1 : mw1;
    float wNW[64], wN[64], wNE[64];
#pragma unroll
    for (int q = 0; q < 64; ++q) {
      wNW[q] = w1g[((ch*64 + q)*3 + 0)*3 + 0];
      wN [q] = w1g[((ch*64 + q)*3 + 0)*3 + 1];
      wNE[q] = w1g[((ch*64 + q)*3 + 0)*3 + 2];
    }
#pragma unroll
    for (int q = 0; q < 64; ++q) {
      asm volatile("" : "+v"(wNW[q]));
      asm volatile("" : "+v"(wN[q]));
      asm volatile("" : "+v"(wNE[q]));
    }
#pragma unroll 1
    for (int p = 0; p < 64; ++p) {
      const int i = p >> 3, j = p & 7;
      const int r = (j >= 2) ? i + 1 : i;       // target row of the task
      const int c = (j >= 2) ? j - 2 : 6 + j;   // target col
      const bool have = (j >= 2) ? (r < 8) : (i >= 1);
      float a0 = 0.f, a1 = 0.f, a2 = 0.f, a3 = 0.f;
      float4 fB = make_float4(0.f,0.f,0.f,0.f), fC = fB;
      if (have) {
        const int sp = (r - 1) & 1;             // source row parity
        const float4 fA = reinterpret_cast<const float4*>(&h0row[net][sp][c    ][0])[ch & 15];
        fB = reinterpret_cast<const float4*>(&h0row[net][sp][c + 1][0])[ch & 15];
        fC = reinterpret_cast<const float4*>(&h0row[net][sp][c + 2][0])[ch & 15];
        DOT16(wNW, fA);
      }
      BAR();
      if (have) {
        DOT16(wN,  fB);
        DOT16(wNE, fC);
        ntap0[net][r & 1][c][ch] = (a0 + a1) + (a2 + a3);
      }
      BAR();
    }

  } else {
    // ========== H1: W2 N-taps vs h1row, same schedule ==========
    const float* w2g = net ? lw2 : mw2;
    float wNW[64], wN[64], wNE[64];
#pragma unroll
    for (int q = 0; q < 64; ++q) {
      wNW[q] = w2g[((ch*64 + q)*3 + 0)*3 + 0];
      wN [q] = w2g[((ch*64 + q)*3 + 0)*3 + 1];
      wNE[q] = w2g[((ch*64 + q)*3 + 0)*3 + 2];
    }
#pragma unroll
    for (int q = 0; q < 64; ++q) {
      asm volatile("" : "+v"(wNW[q]));
      asm volatile("" : "+v"(wN[q]));
      asm volatile("" : "+v"(wNE[q]));
    }
#pragma unroll 1
    for (int p = 0; p < 64; ++p) {
      const int i = p >> 3, j = p & 7;
      const int r = (j >= 2) ? i + 1 : i;
      const int c = (j >= 2) ? j - 2 : 6 + j;
      const bool have = (j >= 2) ? (r < 8) : (i >= 1);
      float a0 = 0.f, a1 = 0.f, a2 = 0.f, a3 = 0.f;
      float4 fB = make_float4(0.f,0.f,0.f,0.f), fC = fB;
      if (have) {
        const int sp = (r - 1) & 1;
        const float4 fA = reinterpret_cast<const float4*>(&h1row[net][sp][c    ][0])[ch & 15];
        fB = reinterpret_cast<const float4*>(&h1row[net][sp][c + 1][0])[ch & 15];
        fC = reinterpret_cast<const float4*>(&h1row[net][sp][c + 2][0])[ch & 15];
        DOT16(wNW, fA);
      }
      BAR();
      if (have) {
        DOT16(wN,  fB);
        DOT16(wNE, fC);
        ntap1[net][r & 1][c][ch] = (a0 + a1) + (a2 + a3);
      }
      BAR();
    }
  }

  BAR();   // join: yb complete (incl. y(63))

  // copy-out: y from yb[0]
  if (tid < 256) {
    const int c = tid >> 6, p = tid & 63;
    out[(b*4 + c)*64 + p] = yb[0][(p >> 3) + 1][(p & 7) + 1][c];
  }
}

extern "C" void kernel_launch(void* const* d_in, const int* in_sizes, int n_in,
                              void* d_out, int out_size, void* d_ws, size_t ws_size,
                              hipStream_t stream) {
  (void)in_sizes; (void)n_in; (void)out_size; (void)d_ws; (void)ws_size;
  made_ar_decode_k<<<dim3(32), dim3(NT), 0, stream>>>(
      (const float*)d_in[0],
      (const float*)d_in[1],  (const float*)d_in[2],
      (const float*)d_in[3],  (const float*)d_in[4],
      (const float*)d_in[5],  (const float*)d_in[6],
      (const float*)d_in[7],  (const float*)d_in[8],
      (const float*)d_in[9],  (const float*)d_in[10],
      (const float*)d_in[11], (const float*)d_in[12],
      (const float*)d_in[13], (const float*)d_in[14],
      (const float*)d_in[15], (const float*)d_in[16],
      (float*)d_out);
}

// Round 9
// 234.591 us; speedup vs baseline: 1.3200x; 1.3200x over previous
//
#include <hip/hip_runtime.h>

// MADE / PixelCNN autoregressive inverse (all fp32, per reference).
//
// r0-r4: 6-barrier/16-wave skeleton pinned at ~179us. r7: 2-barrier/8-wave
// spine+helpers, readlane dots: 146.5us bit-exact, no spill. r8: ntap
// row-ahead + split-across-barrier H state -> scratch spills (WRITE 2.5MB),
// 232us. REVERTED.
//
// r9 = r7 skeleton with cheaper broadcast MACs. The readlane DOT16 pays a
// VALU->SGPR->VALU hazard per MAC (~4-6cy/MAC measured indirectly: r7 5500
// cy/px vs ~2200 issue model). Activations already sit in LDS rows; a
// float4 load at a WAVE-UNIFORM address is one ds_read_b128 broadcast
// (same-address = conflict-free), feeding pure VGPRxVGPR v_fmac: 80 instr
// per 64-dot vs 128, zero SGPR hazards, 16 independent prefetchable loads.
// Applied to all helper dots and the spine center chains (c1 reads back its
// own just-written h0row; c2 its h1row). c1 moved pre-B1 (scalar across
// BAR) to balance phases. Accumulator grouping identical to r7 -> bit-exact.

#define NT 512

__device__ __forceinline__ float elu(float x) { return x > 0.f ? x : expm1f(x); }

#define BAR() asm volatile("s_waitcnt lgkmcnt(0)\n\ts_barrier" ::: "memory")

// 64-dot via uniform-address LDS broadcast: acc{0..3} += W_[4q+m] * B_[4q+m]
#define DOTU(W_, B_)                                                  \
  _Pragma("unroll")                                                   \
  for (int q = 0; q < 16; ++q) {                                      \
    const float4 hq = *reinterpret_cast<const float4*>((B_) + 4*q);   \
    a0 += (W_)[4*q+0] * hq.x;                                         \
    a1 += (W_)[4*q+1] * hq.y;                                         \
    a2 += (W_)[4*q+2] * hq.z;                                         \
    a3 += (W_)[4*q+3] * hq.w;                                         \
  }

__global__ __launch_bounds__(NT)
__attribute__((amdgpu_waves_per_eu(2, 2)))
void made_ar_decode_k(
    const float* __restrict__ x,
    const float* __restrict__ mw0, const float* __restrict__ mb0,
    const float* __restrict__ mw1, const float* __restrict__ mb1,
    const float* __restrict__ mw2, const float* __restrict__ mb2,
    const float* __restrict__ mwo, const float* __restrict__ mbo,
    const float* __restrict__ lw0, const float* __restrict__ lb0,
    const float* __restrict__ lw1, const float* __restrict__ lb1,
    const float* __restrict__ lw2, const float* __restrict__ lb2,
    const float* __restrict__ lwo, const float* __restrict__ lbo,
    float* __restrict__ out)
{
  const int b    = blockIdx.x;
  const int tid  = threadIdx.x;
  const int wave = tid >> 6;       // 0..7
  const int role = wave >> 1;      // 0:S  1:Ha  2:Hb  3:Hc
  const int net  = wave & 1;       // 0 = mu, 1 = lv
  const int ch   = tid & 63;       // lane == out channel

  // row caches, parity double-buffered; col index = spatial col + 1;
  // pad cols 0 and 9 are never written -> permanent zeros ('SAME' border).
  __shared__ __align__(16) float h0row[2][2][10][64]; // [net][par][pcol][ch]
  __shared__ __align__(16) float h1row[2][2][10][64];
  __shared__ __align__(16) float yb[2][9][10][4];     // [net][prow][pcol][c]
  __shared__ __align__(16) float xchg[2][2][4];       // [p&1][net][c] raw sums
  __shared__ float red1a[2][64], red1b[2][64], red2b[2][64], red2c[2][64];
  __shared__ float xls[256];

  for (int k = tid; k < 2*2*10*64; k += NT) {
    (&h0row[0][0][0][0])[k] = 0.f;
    (&h1row[0][0][0][0])[k] = 0.f;
  }
  for (int k = tid; k < 2*9*10*4; k += NT) (&yb[0][0][0][0])[k] = 0.f;
  if (tid < 256) xls[tid] = x[b*256 + tid];   // [c][i][j] flat = c*64 + p

  __syncthreads();   // uniform join after init

  if (role == 0) {
    // ================= S: spine =================
    const float* w0g = net ? lw0 : mw0;
    const float* w1g = net ? lw1 : mw1;
    const float* w2g = net ? lw2 : mw2;
    const float* wog = net ? lwo : mwo;
    const int KH[4] = {0,0,0,1};
    const int KW[4] = {0,1,2,0};
    float waux[16], wc1[64], wc2[64], wo4[4];
#pragma unroll
    for (int t = 0; t < 4; ++t)
#pragma unroll
      for (int ic = 0; ic < 4; ++ic)
        waux[t*4 + ic] = w0g[((ch*4 + ic)*3 + KH[t])*3 + KW[t]];
#pragma unroll
    for (int q = 0; q < 64; ++q) wc1[q] = w1g[((ch*64 + q)*3 + 1)*3 + 1];
#pragma unroll
    for (int q = 0; q < 64; ++q) wc2[q] = w2g[((ch*64 + q)*3 + 1)*3 + 1];
#pragma unroll
    for (int c = 0; c < 4; ++c) wo4[c] = wog[c*64 + ch];
    float bA = (net ? lb0 : mb0)[ch];
    float bB = (net ? lb1 : mb1)[ch];
    float bC = (net ? lb2 : mb2)[ch];
    float boM[4], boL[4];
#pragma unroll
    for (int c = 0; c < 4; ++c) { boM[c] = mbo[c]; boL[c] = lbo[c]; }
#pragma unroll
    for (int k = 0; k < 16; ++k) asm volatile("" : "+v"(waux[k]));
#pragma unroll
    for (int q = 0; q < 64; ++q) asm volatile("" : "+v"(wc1[q]));
#pragma unroll
    for (int q = 0; q < 64; ++q) asm volatile("" : "+v"(wc2[q]));

    float lsacc = 0.f;

#pragma unroll 1
    for (int p = 0; p < 64; ++p) {
      const int i = p >> 3, j = p & 7, cur = i & 1;

      // ---- pre-B1: y-epilogue of p-1, h0(p), center-c1 ----
      if (p > 0) {
        const int pp = p - 1;
        const float4 m4 = *reinterpret_cast<const float4*>(&xchg[pp & 1][0][0]);
        const float4 l4 = *reinterpret_cast<const float4*>(&xchg[pp & 1][1][0]);
        float y0 = (xls[0*64+pp] - (m4.x + boM[0])) / (expf(0.5f*(l4.x + boL[0])) + 1e-12f);
        float y1 = (xls[1*64+pp] - (m4.y + boM[1])) / (expf(0.5f*(l4.y + boL[1])) + 1e-12f);
        float y2 = (xls[2*64+pp] - (m4.z + boM[2])) / (expf(0.5f*(l4.z + boL[2])) + 1e-12f);
        float y3 = (xls[3*64+pp] - (m4.w + boM[3])) / (expf(0.5f*(l4.w + boL[3])) + 1e-12f);
        if (ch == 0)
          *reinterpret_cast<float4*>(&yb[net][(pp>>3)+1][(pp&7)+1][0]) =
              make_float4(y0, y1, y2, y3);
      }
      float acc = bA;
#pragma unroll
      for (int t = 0; t < 4; ++t) {
        const float4 yv = *reinterpret_cast<const float4*>(&yb[net][i + KH[t]][j + KW[t]][0]);
        acc += waux[t*4+0]*yv.x + waux[t*4+1]*yv.y
             + waux[t*4+2]*yv.z + waux[t*4+3]*yv.w;
      }
      const float h0v = elu(acc);
      h0row[net][cur][j + 1][ch] = h0v;

      // center-c1: uniform broadcast read-back of the just-written h0 row
      float c1;
      {
        float a0 = 0.f, a1 = 0.f, a2 = 0.f, a3 = 0.f;
        DOTU(wc1, &h0row[net][cur][j + 1][0]);
        c1 = (a0 + a1) + (a2 + a3);
      }

      BAR();   // B1: h0(p) + helper partials visible

      // ---- post-B1: h1, center-c2, h2, out-conv ----
      const float h1v = elu(c1 + bB + red1a[net][ch] + red1b[net][ch]);
      h1row[net][cur][j + 1][ch] = h1v;

      float c2;
      {
        float a0 = 0.f, a1 = 0.f, a2 = 0.f, a3 = 0.f;
        DOTU(wc2, &h1row[net][cur][j + 1][0]);
        c2 = (a0 + a1) + (a2 + a3);
      }
      const float h2v = elu(c2 + bC + red2b[net][ch] + red2c[net][ch]);

      float s0 = wo4[0]*h2v, s1 = wo4[1]*h2v, s2 = wo4[2]*h2v, s3 = wo4[3]*h2v;
#pragma unroll
      for (int off = 32; off; off >>= 1) {
        s0 += __shfl_xor(s0, off, 64);
        s1 += __shfl_xor(s1, off, 64);
        s2 += __shfl_xor(s2, off, 64);
        s3 += __shfl_xor(s3, off, 64);
      }
      if (ch == 0)
        *reinterpret_cast<float4*>(&xchg[p & 1][net][0]) = make_float4(s0, s1, s2, s3);
      if (net == 1 && ch == 0)
        lsacc += 0.5f*((s0 + boL[0]) + (s1 + boL[1]) + (s2 + boL[2]) + (s3 + boL[3]));

      BAR();   // B2: h1(p), xchg(p) visible for next pixel
    }

    // final y(63) into yb (for the copy-out)
    {
      const float4 m4 = *reinterpret_cast<const float4*>(&xchg[1][0][0]);
      const float4 l4 = *reinterpret_cast<const float4*>(&xchg[1][1][0]);
      float y0 = (xls[0*64+63] - (m4.x + boM[0])) / (expf(0.5f*(l4.x + boL[0])) + 1e-12f);
      float y1 = (xls[1*64+63] - (m4.y + boM[1])) / (expf(0.5f*(l4.y + boL[1])) + 1e-12f);
      float y2 = (xls[2*64+63] - (m4.z + boM[2])) / (expf(0.5f*(l4.z + boL[2])) + 1e-12f);
      float y3 = (xls[3*64+63] - (m4.w + boM[3])) / (expf(0.5f*(l4.w + boL[3])) + 1e-12f);
      if (ch == 0)
        *reinterpret_cast<float4*>(&yb[net][8][8][0]) = make_float4(y0, y1, y2, y3);
    }
    if (net == 1 && ch == 0) out[32*4*64 + b] = lsacc;

  } else if (role == 1) {
    // ================= Ha: W1 {NW, N, NE} vs h0 row i-1 =================
    const float* w1g = net ? lw1 : mw1;
    float wNW[64], wN[64], wNE[64];
#pragma unroll
    for (int q = 0; q < 64; ++q) {
      wNW[q] = w1g[((ch*64 + q)*3 + 0)*3 + 0];
      wN [q] = w1g[((ch*64 + q)*3 + 0)*3 + 1];
      wNE[q] = w1g[((ch*64 + q)*3 + 0)*3 + 2];
    }
#pragma unroll
    for (int q = 0; q < 64; ++q) {
      asm volatile("" : "+v"(wNW[q]));
      asm volatile("" : "+v"(wN[q]));
      asm volatile("" : "+v"(wNE[q]));
    }
#pragma unroll 1
    for (int p = 0; p < 64; ++p) {
      const int i = p >> 3, j = p & 7, prv = (i & 1) ^ 1;
      float a0 = 0.f, a1 = 0.f, a2 = 0.f, a3 = 0.f;
      DOTU(wNW, &h0row[net][prv][j    ][0]);
      DOTU(wN,  &h0row[net][prv][j + 1][0]);
      DOTU(wNE, &h0row[net][prv][j + 2][0]);
      red1a[net][ch] = (a0 + a1) + (a2 + a3);
      BAR();
      BAR();
    }

  } else if (role == 2) {
    // ====== Hb: W1 {W} vs h0(p-1)  +  W2 {NW, N} vs h1 row i-1 ======
    const float* w1g = net ? lw1 : mw1;
    const float* w2g = net ? lw2 : mw2;
    float wW1[64], wNW[64], wN[64];
#pragma unroll
    for (int q = 0; q < 64; ++q) {
      wW1[q] = w1g[((ch*64 + q)*3 + 1)*3 + 0];
      wNW[q] = w2g[((ch*64 + q)*3 + 0)*3 + 0];
      wN [q] = w2g[((ch*64 + q)*3 + 0)*3 + 1];
    }
#pragma unroll
    for (int q = 0; q < 64; ++q) {
      asm volatile("" : "+v"(wW1[q]));
      asm volatile("" : "+v"(wNW[q]));
      asm volatile("" : "+v"(wN[q]));
    }
#pragma unroll 1
    for (int p = 0; p < 64; ++p) {
      const int i = p >> 3, j = p & 7, cur = i & 1, prv = cur ^ 1;
      {
        float a0 = 0.f, a1 = 0.f, a2 = 0.f, a3 = 0.f;
        DOTU(wW1, &h0row[net][cur][j][0]);
        red1b[net][ch] = (a0 + a1) + (a2 + a3);
      }
      {
        float a0 = 0.f, a1 = 0.f, a2 = 0.f, a3 = 0.f;
        DOTU(wNW, &h1row[net][prv][j    ][0]);
        DOTU(wN,  &h1row[net][prv][j + 1][0]);
        red2b[net][ch] = (a0 + a1) + (a2 + a3);
      }
      BAR();
      BAR();
    }

  } else {
    // ====== Hc: W2 {NE} vs h1 row i-1  +  W2 {W} vs h1(p-1) ======
    const float* w2g = net ? lw2 : mw2;
    float wNE[64], wW2[64];
#pragma unroll
    for (int q = 0; q < 64; ++q) {
      wNE[q] = w2g[((ch*64 + q)*3 + 0)*3 + 2];
      wW2[q] = w2g[((ch*64 + q)*3 + 1)*3 + 0];
    }
#pragma unroll
    for (int q = 0; q < 64; ++q) {
      asm volatile("" : "+v"(wNE[q]));
      asm volatile("" : "+v"(wW2[q]));
    }
#pragma unroll 1
    for (int p = 0; p < 64; ++p) {
      const int i = p >> 3, j = p & 7, cur = i & 1, prv = cur ^ 1;
      float a0 = 0.f, a1 = 0.f, a2 = 0.f, a3 = 0.f;
      DOTU(wNE, &h1row[net][prv][j + 2][0]);
      DOTU(wW2, &h1row[net][cur][j    ][0]);
      red2c[net][ch] = (a0 + a1) + (a2 + a3);
      BAR();
      BAR();
    }
  }

  BAR();   // join: yb complete (incl. y(63))

  // copy-out: y from yb[0]
  if (tid < 256) {
    const int c = tid >> 6, p = tid & 63;
    out[(b*4 + c)*64 + p] = yb[0][(p >> 3) + 1][(p & 7) + 1][c];
  }
}

extern "C" void kernel_launch(void* const* d_in, const int* in_sizes, int n_in,
                              void* d_out, int out_size, void* d_ws, size_t ws_size,
                              hipStream_t stream) {
  (void)in_sizes; (void)n_in; (void)out_size; (void)d_ws; (void)ws_size;
  made_ar_decode_k<<<dim3(32), dim3(NT), 0, stream>>>(
      (const float*)d_in[0],
      (const float*)d_in[1],  (const float*)d_in[2],
      (const float*)d_in[3],  (const float*)d_in[4],
      (const float*)d_in[5],  (const float*)d_in[6],
      (const float*)d_in[7],  (const float*)d_in[8],
      (const float*)d_in[9],  (const float*)d_in[10],
      (const float*)d_in[11], (const float*)d_in[12],
      (const float*)d_in[13], (const float*)d_in[14],
      (const float*)d_in[15], (const float*)d_in[16],
      (float*)d_out);
}